// Round 1
// baseline (1223.835 us; speedup 1.0000x reference)
//
#include <hip/hip_runtime.h>

#define N_NODES 50000
#define N_EDGES 600000

// ---------------- degree / norm ----------------

__global__ __launch_bounds__(256) void init_deg(float* deg, int n) {
    int i = blockIdx.x * blockDim.x + threadIdx.x;
    if (i < n) deg[i] = 1.0f;   // +1 from added self-loop
}

__global__ __launch_bounds__(256) void edge_deg(const int* __restrict__ ei,
                                                const float* __restrict__ ew,
                                                float* __restrict__ deg, int E) {
    int e = blockIdx.x * blockDim.x + threadIdx.x;
    if (e < E) {
        int r = ei[e], c = ei[E + e];
        if (r != c) atomicAdd(&deg[c], ew[e]);
    }
}

__global__ __launch_bounds__(256) void finalize_dis(float* deg, int n) {
    int i = blockIdx.x * blockDim.x + threadIdx.x;
    if (i < n) deg[i] = rsqrtf(deg[i]);   // deg >= 1
}

__global__ __launch_bounds__(256) void edge_norm(const int* __restrict__ ei,
                                                 const float* __restrict__ ew,
                                                 const float* __restrict__ dis,
                                                 float* __restrict__ norm, int E) {
    int e = blockIdx.x * blockDim.x + threadIdx.x;
    if (e < E) {
        int r = ei[e], c = ei[E + e];
        norm[e] = (r == c) ? 0.0f : dis[r] * ew[e] * dis[c];
    }
}

// ---------------- fp32 GEMM: out[M][out_ld] (+col0) = A[M][128] @ W[N][128]^T ----------------
// 64x64 output tile per block, K tiled by 64, 4x4 register tile per thread
// (interleaved stride-16 row/col mapping to keep LDS reads ~conflict-free).

__global__ __launch_bounds__(256) void gemm_xwT(const float* __restrict__ A,
                                                const float* __restrict__ W,
                                                float* __restrict__ out,
                                                int M, int out_ld, int out_col0) {
    __shared__ float sx[64 * 68];
    __shared__ float sw[64 * 68];
    const int tid = threadIdx.x;
    const int row0 = blockIdx.y * 64;
    const int col0 = blockIdx.x * 64;   // within W's N dim

    const int tc = tid & 15, tr = tid >> 4;
    float acc[4][4] = {};

    for (int kt = 0; kt < 128; kt += 64) {
        // stage A tile: 64 rows x 16 float4
        #pragma unroll
        for (int i = 0; i < 4; ++i) {
            int f4 = tid + i * 256;            // 0..1023
            int r = f4 >> 4, kk = f4 & 15;
            float4 v = make_float4(0.f, 0.f, 0.f, 0.f);
            int gr = row0 + r;
            if (gr < M) v = reinterpret_cast<const float4*>(A)[gr * 32 + (kt >> 2) + kk];
            *reinterpret_cast<float4*>(&sx[r * 68 + kk * 4]) = v;
        }
        // stage W tile: 64 rows x 16 float4
        #pragma unroll
        for (int i = 0; i < 4; ++i) {
            int f4 = tid + i * 256;
            int r = f4 >> 4, kk = f4 & 15;
            float4 v = reinterpret_cast<const float4*>(W)[(col0 + r) * 32 + (kt >> 2) + kk];
            *reinterpret_cast<float4*>(&sw[r * 68 + kk * 4]) = v;
        }
        __syncthreads();

        #pragma unroll
        for (int k = 0; k < 64; k += 4) {
            float4 xv[4], wv[4];
            #pragma unroll
            for (int i = 0; i < 4; ++i)
                xv[i] = *reinterpret_cast<const float4*>(&sx[(tr + 16 * i) * 68 + k]);
            #pragma unroll
            for (int j = 0; j < 4; ++j)
                wv[j] = *reinterpret_cast<const float4*>(&sw[(tc + 16 * j) * 68 + k]);
            #pragma unroll
            for (int i = 0; i < 4; ++i)
                #pragma unroll
                for (int j = 0; j < 4; ++j)
                    acc[i][j] += xv[i].x * wv[j].x + xv[i].y * wv[j].y +
                                 xv[i].z * wv[j].z + xv[i].w * wv[j].w;
        }
        __syncthreads();
    }

    #pragma unroll
    for (int i = 0; i < 4; ++i) {
        int gr = row0 + tr + 16 * i;
        if (gr < M) {
            #pragma unroll
            for (int j = 0; j < 4; ++j)
                out[gr * out_ld + out_col0 + col0 + tc + 16 * j] = acc[i][j];
        }
    }
}

// ---------------- edge scatter: agg[col] += norm * src[row], 128 ch ----------------
// one wave per edge, float2 per lane

__global__ __launch_bounds__(256) void scatter_edges(const int* __restrict__ ei,
                                                     const float* __restrict__ norm,
                                                     const float* __restrict__ src,
                                                     float* __restrict__ agg, int E) {
    int gt = blockIdx.x * blockDim.x + threadIdx.x;
    int wave = gt >> 6;
    int lane = threadIdx.x & 63;
    int nwaves = (gridDim.x * blockDim.x) >> 6;
    for (int e = wave; e < E; e += nwaves) {
        float nm = norm[e];
        if (nm == 0.f) continue;
        int r = ei[e], c = ei[E + e];
        float2 v = reinterpret_cast<const float2*>(src)[r * 64 + lane];
        atomicAdd(&agg[c * 128 + lane * 2], nm * v.x);
        atomicAdd(&agg[c * 128 + lane * 2 + 1], nm * v.y);
    }
}

// ---------------- combine: h = relu(agg + xw/deg + b), in-place into agg ----------------

__global__ __launch_bounds__(256) void combine_relu(float* __restrict__ agg,
                                                    const float* __restrict__ xw,
                                                    const float* __restrict__ dis,
                                                    const float* __restrict__ b, int n) {
    int idx = blockIdx.x * blockDim.x + threadIdx.x;  // over n*32 float4s
    if (idx >= n * 32) return;
    int i = idx >> 5, c4 = idx & 31;
    float d = dis[i];
    float inv = d * d;   // 1/deg
    float4 a = reinterpret_cast<float4*>(agg)[idx];
    float4 x = reinterpret_cast<const float4*>(xw)[idx];
    float4 bb = reinterpret_cast<const float4*>(b)[c4];
    float4 h;
    h.x = fmaxf(a.x + x.x * inv + bb.x, 0.f);
    h.y = fmaxf(a.y + x.y * inv + bb.y, 0.f);
    h.z = fmaxf(a.z + x.z * inv + bb.z, 0.f);
    h.w = fmaxf(a.w + x.w * inv + bb.w, 0.f);
    reinterpret_cast<float4*>(agg)[idx] = h;
}

// ---------------- final combine: mu / logstd ----------------

__global__ __launch_bounds__(256) void combine_out(const float* __restrict__ agg,
                                                   const float* __restrict__ hw,
                                                   const float* __restrict__ dis,
                                                   const float* __restrict__ bmu,
                                                   const float* __restrict__ bls,
                                                   float* __restrict__ out, int n) {
    int idx = blockIdx.x * blockDim.x + threadIdx.x;  // over n*16 float4s
    if (idx >= n * 16) return;
    int i = idx >> 4, c4 = idx & 15;
    float d = dis[i];
    float inv = d * d;
    // mu (cols 0..63)
    {
        float4 a = reinterpret_cast<const float4*>(agg)[i * 32 + c4];
        float4 x = reinterpret_cast<const float4*>(hw)[i * 32 + c4];
        float4 bb = reinterpret_cast<const float4*>(bmu)[c4];
        float4 o;
        o.x = a.x + x.x * inv + bb.x;
        o.y = a.y + x.y * inv + bb.y;
        o.z = a.z + x.z * inv + bb.z;
        o.w = a.w + x.w * inv + bb.w;
        reinterpret_cast<float4*>(out)[i * 16 + c4] = o;
    }
    // logstd (cols 64..127)
    {
        float4 a = reinterpret_cast<const float4*>(agg)[i * 32 + 16 + c4];
        float4 x = reinterpret_cast<const float4*>(hw)[i * 32 + 16 + c4];
        float4 bb = reinterpret_cast<const float4*>(bls)[c4];
        float4 o;
        o.x = a.x + x.x * inv + bb.x;
        o.y = a.y + x.y * inv + bb.y;
        o.z = a.z + x.z * inv + bb.z;
        o.w = a.w + x.w * inv + bb.w;
        reinterpret_cast<float4*>(out + n * 64)[i * 16 + c4] = o;
    }
}

extern "C" void kernel_launch(void* const* d_in, const int* in_sizes, int n_in,
                              void* d_out, int out_size, void* d_ws, size_t ws_size,
                              hipStream_t stream) {
    const float* x   = (const float*)d_in[0];
    const int*   ei  = (const int*)d_in[1];
    const float* ew  = (const float*)d_in[2];
    const float* W1  = (const float*)d_in[3];
    const float* b1  = (const float*)d_in[4];
    const float* Wmu = (const float*)d_in[5];
    const float* bmu = (const float*)d_in[6];
    const float* Wls = (const float*)d_in[7];
    const float* bls = (const float*)d_in[8];
    float* out = (float*)d_out;

    float* ws   = (float*)d_ws;
    float* deg  = ws;                 // 50000 floats (becomes dis)
    float* norm = ws + 50000;         // 600000
    float* buf0 = ws + 650000;        // 6.4M : xw1, later hw
    float* buf1 = ws + 7050000;       // 6.4M : agg1 -> h -> agg2

    const int N = N_NODES, E = N_EDGES;

    init_deg<<<(N + 255) / 256, 256, 0, stream>>>(deg, N);
    edge_deg<<<(E + 255) / 256, 256, 0, stream>>>(ei, ew, deg, E);
    finalize_dis<<<(N + 255) / 256, 256, 0, stream>>>(deg, N);
    edge_norm<<<(E + 255) / 256, 256, 0, stream>>>(ei, ew, deg, norm, E);

    // layer 1: xw1 = x @ W1^T  [N,128]
    gemm_xwT<<<dim3(2, (N + 63) / 64), 256, 0, stream>>>(x, W1, buf0, N, 128, 0);
    hipMemsetAsync(buf1, 0, (size_t)N * 128 * 4, stream);
    scatter_edges<<<2048, 256, 0, stream>>>(ei, norm, buf0, buf1, E);
    combine_relu<<<(N * 32 + 255) / 256, 256, 0, stream>>>(buf1, buf0, deg, b1, N);

    // layer 2: hw = h @ [Wmu;Wls]^T  [N,128]  (h lives in buf1)
    gemm_xwT<<<dim3(1, (N + 63) / 64), 256, 0, stream>>>(buf1, Wmu, buf0, N, 128, 0);
    gemm_xwT<<<dim3(1, (N + 63) / 64), 256, 0, stream>>>(buf1, Wls, buf0, N, 128, 64);
    hipMemsetAsync(buf1, 0, (size_t)N * 128 * 4, stream);
    scatter_edges<<<2048, 256, 0, stream>>>(ei, norm, buf0, buf1, E);
    combine_out<<<(N * 16 + 255) / 256, 256, 0, stream>>>(buf1, buf0, deg, bmu, bls, out, N);
}

// Round 2
// 398.169 us; speedup vs baseline: 3.0737x; 3.0737x over previous
//
#include <hip/hip_runtime.h>
#include <hip/hip_fp16.h>

#define N_NODES 50000
#define N_EDGES 600000

// ---------------- CSR build ----------------

__global__ __launch_bounds__(256) void init_deg_cnt(float* deg, int* cnt, int n) {
    int i = blockIdx.x * blockDim.x + threadIdx.x;
    if (i < n) { deg[i] = 1.0f; cnt[i] = 0; }   // deg: +1 from added self-loop
}

__global__ __launch_bounds__(256) void hist_edges(const int* __restrict__ ei,
                                                  const float* __restrict__ ew,
                                                  float* __restrict__ deg,
                                                  int* __restrict__ cnt, int E) {
    int e = blockIdx.x * blockDim.x + threadIdx.x;
    if (e < E) {
        int r = ei[e], c = ei[E + e];
        if (r != c) {
            atomicAdd(&deg[c], ew[e]);
            atomicAdd(&cnt[c], 1);
        }
    }
}

__global__ __launch_bounds__(256) void finalize_dis(float* deg, int n) {
    int i = blockIdx.x * blockDim.x + threadIdx.x;
    if (i < n) deg[i] = rsqrtf(deg[i]);   // deg >= 1
}

// exclusive scan of cnt -> start (3 passes)
__global__ __launch_bounds__(256) void scan1(const int* __restrict__ cnt,
                                             int* __restrict__ start,
                                             int* __restrict__ bsum, int n) {
    __shared__ int s[256];
    int t = threadIdx.x, i = blockIdx.x * 256 + t;
    int v = (i < n) ? cnt[i] : 0;
    s[t] = v;
    __syncthreads();
    for (int off = 1; off < 256; off <<= 1) {
        int add = (t >= off) ? s[t - off] : 0;
        __syncthreads();
        s[t] += add;
        __syncthreads();
    }
    if (i < n) start[i] = s[t] - v;          // exclusive within block
    if (t == 255) bsum[blockIdx.x] = s[255]; // block total
}

__global__ __launch_bounds__(256) void scan2(int* __restrict__ bsum,
                                             int* __restrict__ start, int nb, int n) {
    __shared__ int s[256];
    int t = threadIdx.x;
    int v = (t < nb) ? bsum[t] : 0;
    s[t] = v;
    __syncthreads();
    for (int off = 1; off < 256; off <<= 1) {
        int add = (t >= off) ? s[t - off] : 0;
        __syncthreads();
        s[t] += add;
        __syncthreads();
    }
    if (t < nb) bsum[t] = s[t] - v;          // exclusive block offsets
    if (t == nb - 1) start[n] = s[t];        // grand total (unused, for safety)
}

__global__ __launch_bounds__(256) void scan3(int* __restrict__ start,
                                             const int* __restrict__ bsum, int n) {
    int i = blockIdx.x * blockDim.x + threadIdx.x;
    if (i < n) start[i] += bsum[i >> 8];
}

// fill sorted edges; bumps start[c] so that afterwards start[c] = END of node c's
// range, and begin(c) = (c==0) ? 0 : start[c-1].
__global__ __launch_bounds__(256) void fill_edges(const int* __restrict__ ei,
                                                  const float* __restrict__ ew,
                                                  const float* __restrict__ dis,
                                                  int* __restrict__ start,
                                                  unsigned* __restrict__ sed, int E) {
    int e = blockIdx.x * blockDim.x + threadIdx.x;
    if (e >= E) return;
    int r = ei[e], c = ei[E + e];
    if (r == c) return;                      // self-loops dropped (w_eff = 0)
    float v = dis[r] * ew[e] * dis[c];
    unsigned hb = __half_as_ushort(__float2half(v));
    int pos = atomicAdd(&start[c], 1);
    sed[pos] = (hb << 16) | (unsigned)r;     // row in low 16 bits (N < 65536)
}

// ---------------- fp32 GEMM: out[M][out_ld] (+col0) = A[M][128] @ W[N][128]^T ----------------

__global__ __launch_bounds__(256) void gemm_xwT(const float* __restrict__ A,
                                                const float* __restrict__ W,
                                                float* __restrict__ out,
                                                int M, int out_ld, int out_col0) {
    __shared__ float sx[64 * 68];
    __shared__ float sw[64 * 68];
    const int tid = threadIdx.x;
    const int row0 = blockIdx.y * 64;
    const int col0 = blockIdx.x * 64;

    const int tc = tid & 15, tr = tid >> 4;
    float acc[4][4] = {};

    for (int kt = 0; kt < 128; kt += 64) {
        #pragma unroll
        for (int i = 0; i < 4; ++i) {
            int f4 = tid + i * 256;
            int r = f4 >> 4, kk = f4 & 15;
            float4 v = make_float4(0.f, 0.f, 0.f, 0.f);
            int gr = row0 + r;
            if (gr < M) v = reinterpret_cast<const float4*>(A)[gr * 32 + (kt >> 2) + kk];
            *reinterpret_cast<float4*>(&sx[r * 68 + kk * 4]) = v;
        }
        #pragma unroll
        for (int i = 0; i < 4; ++i) {
            int f4 = tid + i * 256;
            int r = f4 >> 4, kk = f4 & 15;
            float4 v = reinterpret_cast<const float4*>(W)[(col0 + r) * 32 + (kt >> 2) + kk];
            *reinterpret_cast<float4*>(&sw[r * 68 + kk * 4]) = v;
        }
        __syncthreads();

        #pragma unroll
        for (int k = 0; k < 64; k += 4) {
            float4 xv[4], wv[4];
            #pragma unroll
            for (int i = 0; i < 4; ++i)
                xv[i] = *reinterpret_cast<const float4*>(&sx[(tr + 16 * i) * 68 + k]);
            #pragma unroll
            for (int j = 0; j < 4; ++j)
                wv[j] = *reinterpret_cast<const float4*>(&sw[(tc + 16 * j) * 68 + k]);
            #pragma unroll
            for (int i = 0; i < 4; ++i)
                #pragma unroll
                for (int j = 0; j < 4; ++j)
                    acc[i][j] += xv[i].x * wv[j].x + xv[i].y * wv[j].y +
                                 xv[i].z * wv[j].z + xv[i].w * wv[j].w;
        }
        __syncthreads();
    }

    #pragma unroll
    for (int i = 0; i < 4; ++i) {
        int gr = row0 + tr + 16 * i;
        if (gr < M) {
            #pragma unroll
            for (int j = 0; j < 4; ++j)
                out[gr * out_ld + out_col0 + col0 + tc + 16 * j] = acc[i][j];
        }
    }
}

// ---------------- CSR gather + fused epilogues ----------------
// one wave per destination node; lane handles channels {2*lane, 2*lane+1}

__global__ __launch_bounds__(256) void gather_relu(const unsigned* __restrict__ sed,
                                                   const int* __restrict__ start,
                                                   const float* __restrict__ dis,
                                                   const float* __restrict__ xw,
                                                   const float* __restrict__ b,
                                                   float* __restrict__ h, int n) {
    int wid = (blockIdx.x * 256 + threadIdx.x) >> 6;
    int lane = threadIdx.x & 63;
    if (wid >= n) return;
    int beg = (wid == 0) ? 0 : start[wid - 1];
    int end = start[wid];
    float2 acc = make_float2(0.f, 0.f);
    for (int p = beg; p < end; ++p) {
        unsigned d = sed[p];
        float nm = __half2float(__ushort_as_half((unsigned short)(d >> 16)));
        int r = d & 0xFFFFu;
        float2 v = reinterpret_cast<const float2*>(xw)[r * 64 + lane];
        acc.x += nm * v.x;
        acc.y += nm * v.y;
    }
    float di = dis[wid];
    float inv = di * di;   // 1/deg
    float2 xv = reinterpret_cast<const float2*>(xw)[wid * 64 + lane];
    float2 bb = reinterpret_cast<const float2*>(b)[lane];
    float2 o;
    o.x = fmaxf(acc.x + xv.x * inv + bb.x, 0.f);
    o.y = fmaxf(acc.y + xv.y * inv + bb.y, 0.f);
    reinterpret_cast<float2*>(h)[wid * 64 + lane] = o;
}

__global__ __launch_bounds__(256) void gather_out(const unsigned* __restrict__ sed,
                                                  const int* __restrict__ start,
                                                  const float* __restrict__ dis,
                                                  const float* __restrict__ hw,
                                                  const float* __restrict__ bmu,
                                                  const float* __restrict__ bls,
                                                  float* __restrict__ out, int n) {
    int wid = (blockIdx.x * 256 + threadIdx.x) >> 6;
    int lane = threadIdx.x & 63;
    if (wid >= n) return;
    int beg = (wid == 0) ? 0 : start[wid - 1];
    int end = start[wid];
    float2 acc = make_float2(0.f, 0.f);
    for (int p = beg; p < end; ++p) {
        unsigned d = sed[p];
        float nm = __half2float(__ushort_as_half((unsigned short)(d >> 16)));
        int r = d & 0xFFFFu;
        float2 v = reinterpret_cast<const float2*>(hw)[r * 64 + lane];
        acc.x += nm * v.x;
        acc.y += nm * v.y;
    }
    float di = dis[wid];
    float inv = di * di;
    float2 xv = reinterpret_cast<const float2*>(hw)[wid * 64 + lane];
    float2 bb = (lane < 32) ? reinterpret_cast<const float2*>(bmu)[lane]
                            : reinterpret_cast<const float2*>(bls)[lane - 32];
    float2 o;
    o.x = acc.x + xv.x * inv + bb.x;
    o.y = acc.y + xv.y * inv + bb.y;
    // cols 0..63 -> mu, cols 64..127 -> logstd
    if (lane < 32)
        reinterpret_cast<float2*>(out)[wid * 32 + lane] = o;
    else
        reinterpret_cast<float2*>(out + (size_t)n * 64)[wid * 32 + (lane - 32)] = o;
}

extern "C" void kernel_launch(void* const* d_in, const int* in_sizes, int n_in,
                              void* d_out, int out_size, void* d_ws, size_t ws_size,
                              hipStream_t stream) {
    const float* x   = (const float*)d_in[0];
    const int*   ei  = (const int*)d_in[1];
    const float* ew  = (const float*)d_in[2];
    const float* W1  = (const float*)d_in[3];
    const float* b1  = (const float*)d_in[4];
    const float* Wmu = (const float*)d_in[5];
    const float* bmu = (const float*)d_in[6];
    const float* Wls = (const float*)d_in[7];
    const float* bls = (const float*)d_in[8];
    float* out = (float*)d_out;

    // workspace layout (u32 units, all chunks 16B-aligned)
    float*    dis   = (float*)d_ws;                    // 50000 (deg -> dis)
    int*      start = (int*)d_ws + 50000;              // 50001
    int*      cnt   = (int*)d_ws + 100004;             // 50000
    int*      bsum  = (int*)d_ws + 150004;             // 256
    unsigned* sed   = (unsigned*)d_ws + 150260;        // 600000
    float*    buf0  = (float*)d_ws + 750260;           // 6.4M  (xw1 -> hw)
    float*    buf1  = (float*)d_ws + 7150260;          // 6.4M  (h)

    const int N = N_NODES, E = N_EDGES;
    const int NB = (N + 255) / 256;   // 196 scan blocks

    // CSR build
    init_deg_cnt<<<NB, 256, 0, stream>>>(dis, cnt, N);
    hist_edges<<<(E + 255) / 256, 256, 0, stream>>>(ei, ew, dis, cnt, E);
    finalize_dis<<<NB, 256, 0, stream>>>(dis, N);
    scan1<<<NB, 256, 0, stream>>>(cnt, start, bsum, N);
    scan2<<<1, 256, 0, stream>>>(bsum, start, NB, N);
    scan3<<<NB, 256, 0, stream>>>(start, bsum, N);
    fill_edges<<<(E + 255) / 256, 256, 0, stream>>>(ei, ew, dis, start, sed, E);

    // layer 1
    gemm_xwT<<<dim3(2, (N + 63) / 64), 256, 0, stream>>>(x, W1, buf0, N, 128, 0);
    gather_relu<<<(N * 64 + 255) / 256, 256, 0, stream>>>(sed, start, dis, buf0, b1, buf1, N);

    // layer 2 (mu and logstd projections side by side in buf0)
    gemm_xwT<<<dim3(1, (N + 63) / 64), 256, 0, stream>>>(buf1, Wmu, buf0, N, 128, 0);
    gemm_xwT<<<dim3(1, (N + 63) / 64), 256, 0, stream>>>(buf1, Wls, buf0, N, 128, 64);
    gather_out<<<(N * 64 + 255) / 256, 256, 0, stream>>>(sed, start, dis, buf0, bmu, bls, out, N);
}

// Round 3
// 261.125 us; speedup vs baseline: 4.6868x; 1.5248x over previous
//
#include <hip/hip_runtime.h>
#include <hip/hip_fp16.h>

#define N_NODES 50000
#define N_EDGES 600000

typedef _Float16 f16;
typedef f16 f16x8 __attribute__((ext_vector_type(8)));
typedef float f32x4 __attribute__((ext_vector_type(4)));
typedef unsigned int u32;
typedef u32 u32x4 __attribute__((ext_vector_type(4)));

// ---------------- CSR build ----------------

__global__ __launch_bounds__(256) void init_deg_cnt(float* deg, int* cnt, int n) {
    int i = blockIdx.x * blockDim.x + threadIdx.x;
    if (i < n) { deg[i] = 1.0f; cnt[i] = 0; }   // deg: +1 from added self-loop
}

__global__ __launch_bounds__(256) void hist_edges(const int* __restrict__ ei,
                                                  const float* __restrict__ ew,
                                                  float* __restrict__ deg,
                                                  int* __restrict__ cnt, int E) {
    int e = blockIdx.x * blockDim.x + threadIdx.x;
    if (e < E) {
        int r = ei[e], c = ei[E + e];
        if (r != c) {
            atomicAdd(&deg[c], ew[e]);
            atomicAdd(&cnt[c], 1);
        }
    }
}

__global__ __launch_bounds__(256) void finalize_dis(float* deg, int n) {
    int i = blockIdx.x * blockDim.x + threadIdx.x;
    if (i < n) deg[i] = rsqrtf(deg[i]);   // deg >= 1
}

// exclusive scan of cnt -> start (3 passes)
__global__ __launch_bounds__(256) void scan1(const int* __restrict__ cnt,
                                             int* __restrict__ start,
                                             int* __restrict__ bsum, int n) {
    __shared__ int s[256];
    int t = threadIdx.x, i = blockIdx.x * 256 + t;
    int v = (i < n) ? cnt[i] : 0;
    s[t] = v;
    __syncthreads();
    for (int off = 1; off < 256; off <<= 1) {
        int add = (t >= off) ? s[t - off] : 0;
        __syncthreads();
        s[t] += add;
        __syncthreads();
    }
    if (i < n) start[i] = s[t] - v;
    if (t == 255) bsum[blockIdx.x] = s[255];
}

__global__ __launch_bounds__(256) void scan2(int* __restrict__ bsum,
                                             int* __restrict__ start, int nb, int n) {
    __shared__ int s[256];
    int t = threadIdx.x;
    int v = (t < nb) ? bsum[t] : 0;
    s[t] = v;
    __syncthreads();
    for (int off = 1; off < 256; off <<= 1) {
        int add = (t >= off) ? s[t - off] : 0;
        __syncthreads();
        s[t] += add;
        __syncthreads();
    }
    if (t < nb) bsum[t] = s[t] - v;
    if (t == nb - 1) start[n] = s[t];
}

__global__ __launch_bounds__(256) void scan3(int* __restrict__ start,
                                             const int* __restrict__ bsum, int n) {
    int i = blockIdx.x * blockDim.x + threadIdx.x;
    if (i < n) start[i] += bsum[i >> 8];
}

// fill sorted edges; bumps start[c]: afterwards start[c] = END of node c's range.
__global__ __launch_bounds__(256) void fill_edges(const int* __restrict__ ei,
                                                  const float* __restrict__ ew,
                                                  const float* __restrict__ dis,
                                                  int* __restrict__ start,
                                                  u32* __restrict__ sed, int E) {
    int e = blockIdx.x * blockDim.x + threadIdx.x;
    if (e >= E) return;
    int r = ei[e], c = ei[E + e];
    if (r == c) return;                      // self-loops dropped (w_eff = 0)
    float v = dis[r] * ew[e] * dis[c];
    u32 hb = __half_as_ushort(__float2half(v));
    int pos = atomicAdd(&start[c], 1);
    sed[pos] = (hb << 16) | (u32)r;          // row in low 16 bits (N < 65536)
}

// ---------------- weight prep: f16, layer-2 concat ----------------

__global__ __launch_bounds__(256) void conv_weights(const float* __restrict__ W1,
                                                    const float* __restrict__ Wmu,
                                                    const float* __restrict__ Wls,
                                                    f16* __restrict__ Wc1,
                                                    f16* __restrict__ Wc2) {
    int i = blockIdx.x * 256 + threadIdx.x;   // 0..16383
    Wc1[i] = (f16)W1[i];
    Wc2[i] = (f16)((i < 8192) ? Wmu[i] : Wls[i - 8192]);
}

// ---------------- MFMA f16 GEMM: C[M][128] f16 = A[M][128] @ Wc[128][128]^T ----------------
// 64x128 tile/block, whole K=128 in LDS, XOR-swizzled 16B chunks.
// mfma_f32_16x16x32_f16: A[m][k] m=lane&15, k=(lane>>4)*8+j; B[k][n] n=lane&15,
// k=(lane>>4)*8+j (B row n read from Wc row n); C/D col=lane&15 row=(lane>>4)*4+reg.

template<bool A_F16>
__global__ __launch_bounds__(256) void gemm_mfma(const void* __restrict__ Aptr,
                                                 const f16* __restrict__ Wc,
                                                 f16* __restrict__ Cout, int M) {
    __shared__ f16 sA[64 * 128];
    __shared__ f16 sW[128 * 128];
    const int tid = threadIdx.x;
    const int row0 = blockIdx.x * 64;

    // stage W: 2048 16B chunks, 8/thread, swizzled by row&15
    {
        const u32x4* src = (const u32x4*)Wc;
        u32x4* dst = (u32x4*)sW;
        #pragma unroll
        for (int i = 0; i < 8; ++i) {
            int c = tid + i * 256;
            int r = c >> 4, ch = c & 15;
            dst[r * 16 + (ch ^ (r & 15))] = src[c];
        }
    }
    // stage A: 1024 16B f16-chunks, 4/thread
    if (A_F16) {
        const u32x4* src = (const u32x4*)Aptr;
        u32x4* dst = (u32x4*)sA;
        #pragma unroll
        for (int i = 0; i < 4; ++i) {
            int c = tid + i * 256;
            int r = c >> 4, ch = c & 15;
            int gr = row0 + r;
            u32x4 v = {};
            if (gr < M) v = src[gr * 16 + ch];
            dst[r * 16 + (ch ^ (r & 15))] = v;
        }
    } else {
        const float4* src = (const float4*)Aptr;
        u32x4* dst = (u32x4*)sA;
        #pragma unroll
        for (int i = 0; i < 4; ++i) {
            int c = tid + i * 256;
            int r = c >> 4, ch = c & 15;
            int gr = row0 + r;
            f16x8 h = {};
            if (gr < M) {
                float4 a = src[gr * 32 + ch * 2];
                float4 b = src[gr * 32 + ch * 2 + 1];
                h[0] = (f16)a.x; h[1] = (f16)a.y; h[2] = (f16)a.z; h[3] = (f16)a.w;
                h[4] = (f16)b.x; h[5] = (f16)b.y; h[6] = (f16)b.z; h[7] = (f16)b.w;
            }
            dst[r * 16 + (ch ^ (r & 15))] = *(const u32x4*)&h;
        }
    }
    __syncthreads();

    const int wave = tid >> 6, lane = tid & 63;
    const int m = lane & 15, kq = lane >> 4;
    const int wcol0 = wave * 32;

    f32x4 acc[4][2] = {};
    const f16x8* sa = (const f16x8*)sA;
    const f16x8* sw = (const f16x8*)sW;

    #pragma unroll
    for (int ks = 0; ks < 4; ++ks) {
        int cidx = ks * 4 + kq;
        f16x8 bfrag[2];
        #pragma unroll
        for (int cf = 0; cf < 2; ++cf) {
            int wr = wcol0 + cf * 16 + m;          // W row = output col
            bfrag[cf] = sw[wr * 16 + (cidx ^ m)];
        }
        #pragma unroll
        for (int rf = 0; rf < 4; ++rf) {
            int ar = rf * 16 + m;
            f16x8 afrag = sa[ar * 16 + (cidx ^ m)];
            #pragma unroll
            for (int cf = 0; cf < 2; ++cf)
                acc[rf][cf] = __builtin_amdgcn_mfma_f32_16x16x32_f16(
                    afrag, bfrag[cf], acc[rf][cf], 0, 0, 0);
        }
    }

    __syncthreads();                 // done reading sA; reuse as output tile
    #pragma unroll
    for (int rf = 0; rf < 4; ++rf)
        #pragma unroll
        for (int cf = 0; cf < 2; ++cf)
            #pragma unroll
            for (int r = 0; r < 4; ++r)
                sA[(rf * 16 + kq * 4 + r) * 128 + wcol0 + cf * 16 + m] =
                    (f16)acc[rf][cf][r];
    __syncthreads();
    {
        const u32x4* src = (const u32x4*)sA;
        u32x4* dst = (u32x4*)Cout;
        #pragma unroll
        for (int i = 0; i < 4; ++i) {
            int c = tid + i * 256;
            int r = c >> 4, ch = c & 15;
            int gr = row0 + r;
            if (gr < M) dst[gr * 16 + ch] = src[c];
        }
    }
}

// ---------------- CSR gather + fused epilogues (f16 src) ----------------
// one wave per destination node; lane handles channels {2*lane, 2*lane+1}

__global__ __launch_bounds__(256) void gather_relu(const u32* __restrict__ sed,
                                                   const int* __restrict__ start,
                                                   const float* __restrict__ dis,
                                                   const f16* __restrict__ xw,
                                                   const float* __restrict__ b,
                                                   f16* __restrict__ h, int n) {
    int wid = (blockIdx.x * 256 + threadIdx.x) >> 6;
    int lane = threadIdx.x & 63;
    if (wid >= n) return;
    int beg = (wid == 0) ? 0 : start[wid - 1];
    int end = start[wid];
    const __half2* src = (const __half2*)xw;
    float ax = 0.f, ay = 0.f;
    for (int p = beg; p < end; ++p) {
        u32 d = sed[p];
        float nm = __half2float(__ushort_as_half((unsigned short)(d >> 16)));
        int r = d & 0xFFFFu;
        float2 v = __half22float2(src[r * 64 + lane]);
        ax += nm * v.x;
        ay += nm * v.y;
    }
    float di = dis[wid];
    float inv = di * di;           // 1/deg
    float2 xv = __half22float2(src[wid * 64 + lane]);
    float2 bb = reinterpret_cast<const float2*>(b)[lane];
    float ox = fmaxf(ax + xv.x * inv + bb.x, 0.f);
    float oy = fmaxf(ay + xv.y * inv + bb.y, 0.f);
    reinterpret_cast<__half2*>(h)[wid * 64 + lane] = __floats2half2_rn(ox, oy);
}

__global__ __launch_bounds__(256) void gather_out(const u32* __restrict__ sed,
                                                  const int* __restrict__ start,
                                                  const float* __restrict__ dis,
                                                  const f16* __restrict__ hw,
                                                  const float* __restrict__ bmu,
                                                  const float* __restrict__ bls,
                                                  float* __restrict__ out, int n) {
    int wid = (blockIdx.x * 256 + threadIdx.x) >> 6;
    int lane = threadIdx.x & 63;
    if (wid >= n) return;
    int beg = (wid == 0) ? 0 : start[wid - 1];
    int end = start[wid];
    const __half2* src = (const __half2*)hw;
    float ax = 0.f, ay = 0.f;
    for (int p = beg; p < end; ++p) {
        u32 d = sed[p];
        float nm = __half2float(__ushort_as_half((unsigned short)(d >> 16)));
        int r = d & 0xFFFFu;
        float2 v = __half22float2(src[r * 64 + lane]);
        ax += nm * v.x;
        ay += nm * v.y;
    }
    float di = dis[wid];
    float inv = di * di;
    float2 xv = __half22float2(src[wid * 64 + lane]);
    float2 bb = (lane < 32) ? reinterpret_cast<const float2*>(bmu)[lane]
                            : reinterpret_cast<const float2*>(bls)[lane - 32];
    float2 o = make_float2(ax + xv.x * inv + bb.x, ay + xv.y * inv + bb.y);
    if (lane < 32)
        reinterpret_cast<float2*>(out)[wid * 32 + lane] = o;                       // mu
    else
        reinterpret_cast<float2*>(out + (size_t)n * 64)[wid * 32 + (lane - 32)] = o; // logstd
}

extern "C" void kernel_launch(void* const* d_in, const int* in_sizes, int n_in,
                              void* d_out, int out_size, void* d_ws, size_t ws_size,
                              hipStream_t stream) {
    const float* x   = (const float*)d_in[0];
    const int*   ei  = (const int*)d_in[1];
    const float* ew  = (const float*)d_in[2];
    const float* W1  = (const float*)d_in[3];
    const float* b1  = (const float*)d_in[4];
    const float* Wmu = (const float*)d_in[5];
    const float* bmu = (const float*)d_in[6];
    const float* Wls = (const float*)d_in[7];
    const float* bls = (const float*)d_in[8];
    float* out = (float*)d_out;

    // workspace layout (u32 units; all bases 16B-aligned)
    float* dis   = (float*)d_ws;                   // 50000
    int*   start = (int*)d_ws + 50000;             // 50001 (+pad)
    int*   cnt   = (int*)d_ws + 100004;            // 50000
    int*   bsum  = (int*)d_ws + 150004;            // 256
    u32*   sed   = (u32*)d_ws + 150260;            // 600000
    f16*   Wc1   = (f16*)((u32*)d_ws + 750260);    // 16384 f16
    f16*   Wc2   = (f16*)((u32*)d_ws + 758452);    // 16384 f16
    f16*   bufA  = (f16*)((u32*)d_ws + 766644);    // 50000*128 f16 (xw -> hw)
    f16*   bufH  = (f16*)((u32*)d_ws + 3966644);   // 50000*128 f16 (h)

    const int N = N_NODES, E = N_EDGES;
    const int NB = (N + 255) / 256;   // 196

    // CSR build
    init_deg_cnt<<<NB, 256, 0, stream>>>(dis, cnt, N);
    hist_edges<<<(E + 255) / 256, 256, 0, stream>>>(ei, ew, dis, cnt, E);
    finalize_dis<<<NB, 256, 0, stream>>>(dis, N);
    scan1<<<NB, 256, 0, stream>>>(cnt, start, bsum, N);
    scan2<<<1, 256, 0, stream>>>(bsum, start, NB, N);
    scan3<<<NB, 256, 0, stream>>>(start, bsum, N);
    fill_edges<<<(E + 255) / 256, 256, 0, stream>>>(ei, ew, dis, start, sed, E);

    conv_weights<<<64, 256, 0, stream>>>(W1, Wmu, Wls, Wc1, Wc2);

    // layer 1
    gemm_mfma<false><<<(N + 63) / 64, 256, 0, stream>>>(x, Wc1, bufA, N);
    gather_relu<<<(N * 64 + 255) / 256, 256, 0, stream>>>(sed, start, dis, bufA, b1, bufH, N);

    // layer 2 (mu‖logstd in one GEMM)
    gemm_mfma<true><<<(N + 63) / 64, 256, 0, stream>>>(bufH, Wc2, bufA, N);
    gather_out<<<(N * 64 + 255) / 256, 256, 0, stream>>>(sed, start, dis, bufA, bmu, bls, out, N);
}

// Round 4
// 243.630 us; speedup vs baseline: 5.0233x; 1.0718x over previous
//
#include <hip/hip_runtime.h>
#include <hip/hip_fp16.h>

#define N_NODES 50000
#define N_EDGES 600000

typedef _Float16 f16;
typedef f16 f16x8 __attribute__((ext_vector_type(8)));
typedef float f32x4 __attribute__((ext_vector_type(4)));
typedef unsigned int u32;
typedef u32 u32x4 __attribute__((ext_vector_type(4)));

// ---------------- CSR build ----------------

__global__ __launch_bounds__(256) void init_deg_cnt(float* deg, int* cnt, int n) {
    int i = blockIdx.x * blockDim.x + threadIdx.x;
    if (i < n) { deg[i] = 1.0f; cnt[i] = 0; }   // deg: +1 from added self-loop
}

__global__ __launch_bounds__(256) void hist_edges(const int* __restrict__ ei,
                                                  const float* __restrict__ ew,
                                                  float* __restrict__ deg,
                                                  int* __restrict__ cnt, int E) {
    int e = blockIdx.x * blockDim.x + threadIdx.x;
    if (e < E) {
        int r = ei[e], c = ei[E + e];
        if (r != c) {
            atomicAdd(&deg[c], ew[e]);
            atomicAdd(&cnt[c], 1);
        }
    }
}

__global__ __launch_bounds__(256) void finalize_dis(float* deg, int n) {
    int i = blockIdx.x * blockDim.x + threadIdx.x;
    if (i < n) deg[i] = rsqrtf(deg[i]);   // deg >= 1
}

// exclusive scan of cnt -> start (3 passes)
__global__ __launch_bounds__(256) void scan1(const int* __restrict__ cnt,
                                             int* __restrict__ start,
                                             int* __restrict__ bsum, int n) {
    __shared__ int s[256];
    int t = threadIdx.x, i = blockIdx.x * 256 + t;
    int v = (i < n) ? cnt[i] : 0;
    s[t] = v;
    __syncthreads();
    for (int off = 1; off < 256; off <<= 1) {
        int add = (t >= off) ? s[t - off] : 0;
        __syncthreads();
        s[t] += add;
        __syncthreads();
    }
    if (i < n) start[i] = s[t] - v;
    if (t == 255) bsum[blockIdx.x] = s[255];
}

__global__ __launch_bounds__(256) void scan2(int* __restrict__ bsum,
                                             int* __restrict__ start, int nb, int n) {
    __shared__ int s[256];
    int t = threadIdx.x;
    int v = (t < nb) ? bsum[t] : 0;
    s[t] = v;
    __syncthreads();
    for (int off = 1; off < 256; off <<= 1) {
        int add = (t >= off) ? s[t - off] : 0;
        __syncthreads();
        s[t] += add;
        __syncthreads();
    }
    if (t < nb) bsum[t] = s[t] - v;
    if (t == nb - 1) start[n] = s[t];
}

__global__ __launch_bounds__(256) void scan3(int* __restrict__ start,
                                             const int* __restrict__ bsum, int n) {
    int i = blockIdx.x * blockDim.x + threadIdx.x;
    if (i < n) start[i] += bsum[i >> 8];
}

// fill sorted edges; bumps start[c]: afterwards start[c] = END of node c's range.
__global__ __launch_bounds__(256) void fill_edges(const int* __restrict__ ei,
                                                  const float* __restrict__ ew,
                                                  const float* __restrict__ dis,
                                                  int* __restrict__ start,
                                                  u32* __restrict__ sed, int E) {
    int e = blockIdx.x * blockDim.x + threadIdx.x;
    if (e >= E) return;
    int r = ei[e], c = ei[E + e];
    if (r == c) return;                      // self-loops dropped (w_eff = 0)
    float v = dis[r] * ew[e] * dis[c];
    u32 hb = __half_as_ushort(__float2half(v));
    int pos = atomicAdd(&start[c], 1);
    sed[pos] = (hb << 16) | (u32)r;          // row in low 16 bits (N < 65536)
}

// ---------------- weight prep: f16, layer-2 concat ----------------

__global__ __launch_bounds__(256) void conv_weights(const float* __restrict__ W1,
                                                    const float* __restrict__ Wmu,
                                                    const float* __restrict__ Wls,
                                                    f16* __restrict__ Wc1,
                                                    f16* __restrict__ Wc2) {
    int i = blockIdx.x * 256 + threadIdx.x;   // 0..16383
    Wc1[i] = (f16)W1[i];
    Wc2[i] = (f16)((i < 8192) ? Wmu[i] : Wls[i - 8192]);
}

// ---------------- MFMA f16 GEMM: C = A[M][128] @ Wc[128][128]^T ----------------
// Output written channel-split: C_lo[M][64], C_hi[M][64] (f16).
// 64x128 tile/block, whole K=128 in LDS, XOR-swizzled 16B chunks.

template<bool A_F16>
__global__ __launch_bounds__(256) void gemm_mfma(const void* __restrict__ Aptr_lo,
                                                 const void* __restrict__ Aptr_hi,
                                                 const f16* __restrict__ Wc,
                                                 f16* __restrict__ C_lo,
                                                 f16* __restrict__ C_hi, int M) {
    __shared__ f16 sA[64 * 128];
    __shared__ f16 sW[128 * 128];
    const int tid = threadIdx.x;
    const int row0 = blockIdx.x * 64;

    // stage W: 2048 16B chunks, 8/thread, swizzled by row&15
    {
        const u32x4* src = (const u32x4*)Wc;
        u32x4* dst = (u32x4*)sW;
        #pragma unroll
        for (int i = 0; i < 8; ++i) {
            int c = tid + i * 256;
            int r = c >> 4, ch = c & 15;
            dst[r * 16 + (ch ^ (r & 15))] = src[c];
        }
    }
    // stage A: 1024 16B f16-chunks, 4/thread
    if (A_F16) {
        const u32x4* slo = (const u32x4*)Aptr_lo;
        const u32x4* shi = (const u32x4*)Aptr_hi;
        u32x4* dst = (u32x4*)sA;
        #pragma unroll
        for (int i = 0; i < 4; ++i) {
            int c = tid + i * 256;
            int r = c >> 4, ch = c & 15;
            int gr = row0 + r;
            u32x4 v = {};
            if (gr < M) v = (ch < 8) ? slo[gr * 8 + ch] : shi[gr * 8 + ch - 8];
            dst[r * 16 + (ch ^ (r & 15))] = v;
        }
    } else {
        const float4* src = (const float4*)Aptr_lo;   // fp32 x, single buffer
        u32x4* dst = (u32x4*)sA;
        #pragma unroll
        for (int i = 0; i < 4; ++i) {
            int c = tid + i * 256;
            int r = c >> 4, ch = c & 15;
            int gr = row0 + r;
            f16x8 h = {};
            if (gr < M) {
                float4 a = src[gr * 32 + ch * 2];
                float4 b = src[gr * 32 + ch * 2 + 1];
                h[0] = (f16)a.x; h[1] = (f16)a.y; h[2] = (f16)a.z; h[3] = (f16)a.w;
                h[4] = (f16)b.x; h[5] = (f16)b.y; h[6] = (f16)b.z; h[7] = (f16)b.w;
            }
            dst[r * 16 + (ch ^ (r & 15))] = *(const u32x4*)&h;
        }
    }
    __syncthreads();

    const int wave = tid >> 6, lane = tid & 63;
    const int m = lane & 15, kq = lane >> 4;
    const int wcol0 = wave * 32;

    f32x4 acc[4][2] = {};
    const f16x8* sa = (const f16x8*)sA;
    const f16x8* sw = (const f16x8*)sW;

    #pragma unroll
    for (int ks = 0; ks < 4; ++ks) {
        int cidx = ks * 4 + kq;
        f16x8 bfrag[2];
        #pragma unroll
        for (int cf = 0; cf < 2; ++cf) {
            int wr = wcol0 + cf * 16 + m;          // W row = output col
            bfrag[cf] = sw[wr * 16 + (cidx ^ m)];
        }
        #pragma unroll
        for (int rf = 0; rf < 4; ++rf) {
            int ar = rf * 16 + m;
            f16x8 afrag = sa[ar * 16 + (cidx ^ m)];
            #pragma unroll
            for (int cf = 0; cf < 2; ++cf)
                acc[rf][cf] = __builtin_amdgcn_mfma_f32_16x16x32_f16(
                    afrag, bfrag[cf], acc[rf][cf], 0, 0, 0);
        }
    }

    __syncthreads();                 // done reading sA; reuse as output tile
    #pragma unroll
    for (int rf = 0; rf < 4; ++rf)
        #pragma unroll
        for (int cf = 0; cf < 2; ++cf)
            #pragma unroll
            for (int r = 0; r < 4; ++r)
                sA[(rf * 16 + kq * 4 + r) * 128 + wcol0 + cf * 16 + m] =
                    (f16)acc[rf][cf][r];
    __syncthreads();
    {
        const u32x4* src = (const u32x4*)sA;
        u32x4* dlo = (u32x4*)C_lo;
        u32x4* dhi = (u32x4*)C_hi;
        #pragma unroll
        for (int i = 0; i < 4; ++i) {
            int c = tid + i * 256;
            int r = c >> 4, ch = c & 15;
            int gr = row0 + r;
            if (gr < M) {
                if (ch < 8) dlo[gr * 8 + ch] = src[c];
                else        dhi[gr * 8 + ch - 8] = src[c];
            }
        }
    }
}

// ---------------- CSR gather + fused epilogues (channel-split f16 src) ----------------
// wave per (node, half); half = blockIdx&1 so even/odd XCDs see disjoint 6.4MB buffers.
// lane = one channel of the 64 in this half; 4-deep unrolled edge loop for MLP.

#define NM(d) __half2float(__ushort_as_half((unsigned short)((d) >> 16)))

__global__ __launch_bounds__(256) void gather_relu(const u32* __restrict__ sed,
                                                   const int* __restrict__ start,
                                                   const float* __restrict__ dis,
                                                   const f16* __restrict__ xw_lo,
                                                   const f16* __restrict__ xw_hi,
                                                   const float* __restrict__ b,
                                                   f16* __restrict__ h_lo,
                                                   f16* __restrict__ h_hi, int n) {
    int bid = blockIdx.x;
    int half = bid & 1;
    int wid = (bid >> 1) * 4 + (threadIdx.x >> 6);
    int lane = threadIdx.x & 63;
    if (wid >= n) return;
    const f16* src = half ? xw_hi : xw_lo;
    f16*       dst = half ? h_hi : h_lo;
    int beg = (wid == 0) ? 0 : start[wid - 1];
    int end = start[wid];
    float acc = 0.f;
    int p = beg;
    for (; p + 4 <= end; p += 4) {
        u32 d0 = sed[p], d1 = sed[p + 1], d2 = sed[p + 2], d3 = sed[p + 3];
        float v0 = (float)src[(d0 & 0xFFFFu) * 64 + lane];
        float v1 = (float)src[(d1 & 0xFFFFu) * 64 + lane];
        float v2 = (float)src[(d2 & 0xFFFFu) * 64 + lane];
        float v3 = (float)src[(d3 & 0xFFFFu) * 64 + lane];
        acc += NM(d0) * v0 + NM(d1) * v1 + NM(d2) * v2 + NM(d3) * v3;
    }
    for (; p < end; ++p) {
        u32 d = sed[p];
        acc += NM(d) * (float)src[(d & 0xFFFFu) * 64 + lane];
    }
    float di = dis[wid];
    float inv = di * di;   // 1/deg
    float xv = (float)src[wid * 64 + lane];
    float o = fmaxf(acc + xv * inv + b[half * 64 + lane], 0.f);
    dst[wid * 64 + lane] = (f16)o;
}

__global__ __launch_bounds__(256) void gather_out(const u32* __restrict__ sed,
                                                  const int* __restrict__ start,
                                                  const float* __restrict__ dis,
                                                  const f16* __restrict__ hw_lo,
                                                  const f16* __restrict__ hw_hi,
                                                  const float* __restrict__ bmu,
                                                  const float* __restrict__ bls,
                                                  float* __restrict__ out, int n) {
    int bid = blockIdx.x;
    int half = bid & 1;
    int wid = (bid >> 1) * 4 + (threadIdx.x >> 6);
    int lane = threadIdx.x & 63;
    if (wid >= n) return;
    const f16* src = half ? hw_hi : hw_lo;
    const float* bb = half ? bls : bmu;
    int beg = (wid == 0) ? 0 : start[wid - 1];
    int end = start[wid];
    float acc = 0.f;
    int p = beg;
    for (; p + 4 <= end; p += 4) {
        u32 d0 = sed[p], d1 = sed[p + 1], d2 = sed[p + 2], d3 = sed[p + 3];
        float v0 = (float)src[(d0 & 0xFFFFu) * 64 + lane];
        float v1 = (float)src[(d1 & 0xFFFFu) * 64 + lane];
        float v2 = (float)src[(d2 & 0xFFFFu) * 64 + lane];
        float v3 = (float)src[(d3 & 0xFFFFu) * 64 + lane];
        acc += NM(d0) * v0 + NM(d1) * v1 + NM(d2) * v2 + NM(d3) * v3;
    }
    for (; p < end; ++p) {
        u32 d = sed[p];
        acc += NM(d) * (float)src[(d & 0xFFFFu) * 64 + lane];
    }
    float di = dis[wid];
    float inv = di * di;
    float xv = (float)src[wid * 64 + lane];
    // half 0 -> mu block, half 1 -> logstd block
    out[(size_t)half * n * 64 + (size_t)wid * 64 + lane] = acc + xv * inv + bb[lane];
}

extern "C" void kernel_launch(void* const* d_in, const int* in_sizes, int n_in,
                              void* d_out, int out_size, void* d_ws, size_t ws_size,
                              hipStream_t stream) {
    const float* x   = (const float*)d_in[0];
    const int*   ei  = (const int*)d_in[1];
    const float* ew  = (const float*)d_in[2];
    const float* W1  = (const float*)d_in[3];
    const float* b1  = (const float*)d_in[4];
    const float* Wmu = (const float*)d_in[5];
    const float* bmu = (const float*)d_in[6];
    const float* Wls = (const float*)d_in[7];
    const float* bls = (const float*)d_in[8];
    float* out = (float*)d_out;

    // workspace layout (u32 units; all bases 16B-aligned)
    float* dis   = (float*)d_ws;                    // 50000
    int*   start = (int*)d_ws + 50000;              // 50001 (+pad)
    int*   cnt   = (int*)d_ws + 100004;             // 50000
    int*   bsum  = (int*)d_ws + 150004;             // 256
    u32*   sed   = (u32*)d_ws + 150260;             // 600000
    f16*   Wc1   = (f16*)((u32*)d_ws + 750260);     // 16384 f16
    f16*   Wc2   = (f16*)((u32*)d_ws + 758452);     // 16384 f16
    f16*   A_lo  = (f16*)((u32*)d_ws + 766644);     // 50000*64 f16 (xw/hw lo)
    f16*   A_hi  = (f16*)((u32*)d_ws + 2366644);    // 50000*64 f16
    f16*   H_lo  = (f16*)((u32*)d_ws + 3966644);    // 50000*64 f16 (h lo)
    f16*   H_hi  = (f16*)((u32*)d_ws + 5566644);    // 50000*64 f16

    const int N = N_NODES, E = N_EDGES;
    const int NB = (N + 255) / 256;   // 196
    const int GB = 2 * ((N + 3) / 4); // gather blocks: (node-group, half)

    // CSR build
    init_deg_cnt<<<NB, 256, 0, stream>>>(dis, cnt, N);
    hist_edges<<<(E + 255) / 256, 256, 0, stream>>>(ei, ew, dis, cnt, E);
    finalize_dis<<<NB, 256, 0, stream>>>(dis, N);
    scan1<<<NB, 256, 0, stream>>>(cnt, start, bsum, N);
    scan2<<<1, 256, 0, stream>>>(bsum, start, NB, N);
    scan3<<<NB, 256, 0, stream>>>(start, bsum, N);
    fill_edges<<<(E + 255) / 256, 256, 0, stream>>>(ei, ew, dis, start, sed, E);

    conv_weights<<<64, 256, 0, stream>>>(W1, Wmu, Wls, Wc1, Wc2);

    // layer 1
    gemm_mfma<false><<<(N + 63) / 64, 256, 0, stream>>>(x, nullptr, Wc1, A_lo, A_hi, N);
    gather_relu<<<GB, 256, 0, stream>>>(sed, start, dis, A_lo, A_hi, b1, H_lo, H_hi, N);

    // layer 2 (mu‖logstd in one GEMM)
    gemm_mfma<true><<<(N + 63) / 64, 256, 0, stream>>>(H_lo, H_hi, Wc2, A_lo, A_hi, N);
    gather_out<<<GB, 256, 0, stream>>>(sed, start, dis, A_lo, A_hi, bmu, bls, out, N);
}